// Round 8
// baseline (1008.823 us; speedup 1.0000x reference)
//
#include <hip/hip_runtime.h>
#include <hip/hip_bf16.h>
#include <math.h>

// Pattern-aware MoE, MI355X. Sparse top-2 dispatch with bf16 MFMA grouped GEMMs.
// B=8 S=4096 D=512 H=2048 E=8 P=16 K=2.
// R10: R9 (H-halved full expert fusion, 4 GEMM dispatches) + XCD-aware
//   expert-per-XCD block swizzle in both GEMMs.
//   flat hw id w -> work = (w&7)*(W/8) + (w>>3), decoded n-fastest:
//   each XCD owns ONE expert's half-GEMM -> the 16 (gemm1) / 4 (gemm2)
//   N-blocks sharing an A-tile run on one XCD (A fetched once, was 8x:
//   R9 FETCH 280MB vs 50MB unique) and the expert's B-half (2.1/1 MB)
//   stays resident in that XCD's 4MB L2. Bijective (W%8==0) -> correctness
//   independent of the XCD round-robin assumption.

#define B_ 8
#define S_ 4096
#define D_ 512
#define H_ 2048
#define HH (H_ / 2)         // 1024 half width
#define E_ 8
#define P_ 16
#define NTOK (B_ * S_)      // 32768
#define NPAIR (NTOK * 2)    // 65536

typedef __bf16 bf16;
typedef __bf16 bf16x8 __attribute__((ext_vector_type(8)));
typedef float f32x4 __attribute__((ext_vector_type(4)));

// ---- workspace layout (bytes) ----
#define OFF_GATES 256
#define OFF_LIST (OFF_GATES + NPAIR * 4)
#define OFF_XBF (OFF_LIST + E_ * NTOK * 4)
#define OFF_W13T (OFF_XBF + (size_t)NTOK * D_ * 2)                // [E][2H][D] interleaved
#define OFF_W2T (OFF_W13T + (size_t)E_ * 2 * H_ * D_ * 2)
#define OFF_HBUF (OFF_W2T + (size_t)E_ * D_ * H_ * 2)
#define WS_NEEDED (OFF_HBUF + (size_t)NPAIR * HH * 2)  // ~209 MiB

// async global->LDS, 16B per lane; LDS dest = base + lane*16 (wave-uniform base)
__device__ __forceinline__ void gl16(const bf16* g, bf16* l) {
  __builtin_amdgcn_global_load_lds((const __attribute__((address_space(1))) unsigned int*)g,
                                   (__attribute__((address_space(3))) unsigned int*)l, 16, 0, 0);
}

// ============================ router =====================================
__global__ __launch_bounds__(256) void router_kernel(
    const float* __restrict__ x, const int* __restrict__ pids,
    const float* __restrict__ Wr, const float* __restrict__ Wp,
    bf16* __restrict__ xbf, float* __restrict__ gates, int* __restrict__ lists,
    int* __restrict__ counts, float* __restrict__ probSum, float* __restrict__ zSum) {
  __shared__ float xs[32 * 516];     // stride 516: 8 rows/wave land on distinct banks
  __shared__ float wr_s[E_ * 516];   // [e][d], stride 516
  __shared__ float wp_s[E_];
  __shared__ float probAcc[E_];
  __shared__ float zAcc;
  __shared__ int lcnt[E_], lbase[E_];
  __shared__ float lg_s[32][E_ + 1];

  const int tid = threadIdx.x;
  const int tok0 = blockIdx.x * 32;

  // Wr is [D][E] -> wr_s[e*516 + d]
#pragma unroll
  for (int rep = 0; rep < (D_ * E_) / 256; ++rep) {
    int flat = rep * 256 + tid;
    wr_s[(flat & 7) * 516 + (flat >> 3)] = Wr[flat];
  }
  if (tid < E_) {
    wp_s[tid] = Wp[pids[tok0 >> 12] * E_ + tid];  // blocks never straddle batch rows
    probAcc[tid] = 0.f;
    lcnt[tid] = 0;
  }
  if (tid == 0) zAcc = 0.f;

  // stage x tile + write bf16 copy (both coalesced)
  const float4* x4 = (const float4*)(x + (size_t)tok0 * D_);
#pragma unroll
  for (int rep = 0; rep < 16; ++rep) {
    int idx = rep * 256 + tid;  // float4 index in 32x512 tile
    float4 v = x4[idx];
    int t = idx >> 7;           // 128 float4 per row
    int d = (idx & 127) * 4;
    *(float4*)(xs + t * 516 + d) = v;
    union { unsigned short u[4]; uint2 qq; } pk;
    pk.u[0] = __builtin_bit_cast(unsigned short, (bf16)v.x);
    pk.u[1] = __builtin_bit_cast(unsigned short, (bf16)v.y);
    pk.u[2] = __builtin_bit_cast(unsigned short, (bf16)v.z);
    pk.u[3] = __builtin_bit_cast(unsigned short, (bf16)v.w);
    *(uint2*)(xbf + (size_t)tok0 * D_ + (size_t)idx * 4) = pk.qq;
  }
  __syncthreads();

  const int t = tid >> 3, e = tid & 7;
  const int lane = tid & 63;
  {
    float a0 = 0.f, a1 = 0.f, a2 = 0.f, a3 = 0.f;
    const float* xr = xs + t * 516;
    const float* wr = wr_s + e * 516;
#pragma unroll 8
    for (int d = 0; d < D_; d += 4) {
      float4 xv = *(const float4*)(xr + d);
      float4 wv = *(const float4*)(wr + d);
      a0 += xv.x * wv.x;
      a1 += xv.y * wv.y;
      a2 += xv.z * wv.z;
      a3 += xv.w * wv.w;
    }
    lg_s[t][e] = (a0 + a1) + (a2 + a3) + wp_s[e];
  }
  __syncthreads();

  float v[E_];
#pragma unroll
  for (int k = 0; k < E_; ++k) v[k] = lg_s[t][k];
  const float lg = v[e];
  float m = v[0];
#pragma unroll
  for (int k = 1; k < E_; ++k) m = fmaxf(m, v[k]);
  float s = 0.f;
#pragma unroll
  for (int k = 0; k < E_; ++k) s += expf(v[k] - m);
  float prob = expf(lg - m) / s;
  float z = lg * lg;
  // top-2 (ties -> lower index, matching lax.top_k)
  int i1 = 0;
  float v1 = v[0];
#pragma unroll
  for (int k = 1; k < E_; ++k)
    if (v[k] > v1) { v1 = v[k]; i1 = k; }
  int i2 = -1;
  float v2 = -1e30f;
#pragma unroll
  for (int k = 0; k < E_; ++k)
    if (k != i1 && v[k] > v2) { v2 = v[k]; i2 = k; }

  // stats reductions: same-e lanes are stride-8 within the wave
  float p = prob;
  p += __shfl_xor(p, 8);
  p += __shfl_xor(p, 16);
  p += __shfl_xor(p, 32);
  float zz = z;
#pragma unroll
  for (int off = 1; off < 64; off <<= 1) zz += __shfl_xor(zz, off);
  if (lane < 8) atomicAdd(&probAcc[e], p);
  if (lane == 0) atomicAdd(&zAcc, zz);

  // selection + local list append
  int r = (e == i1) ? 0 : ((e == i2) ? 1 : -1);
  int pos = -1;
  if (r >= 0) {
    float ex = expf(v2 - v1);
    float g = (r == 0) ? 1.f / (1.f + ex) : ex / (1.f + ex);
    gates[(tok0 + t) * 2 + r] = g;
    pos = atomicAdd(&lcnt[e], 1);
  }
  __syncthreads();
  if (tid < E_) lbase[tid] = atomicAdd(&counts[tid], lcnt[tid]);
  __syncthreads();
  if (r >= 0) lists[e * NTOK + lbase[e] + pos] = (tok0 + t) * 2 + r;
  if (tid < E_) atomicAdd(&probSum[tid], probAcc[tid]);
  else if (tid == 8) atomicAdd(zSum, zAcc);
}

// ======================= transpose + fp32->bf16 ==========================
// mode < 0: plain transpose. mode >= 0: W13T interleave remap:
// out row = ((h>>4)<<5) | (h&15) | mode  (mode=0 W1, mode=16 W3).
__global__ __launch_bounds__(256) void transpose_convert(const float* __restrict__ in,
                                                         bf16* __restrict__ out, int R, int C,
                                                         size_t out_estride, int mode) {
  const int e = blockIdx.z;
  const int r0 = blockIdx.y * 64, c0 = blockIdx.x * 64;
  in += (size_t)e * R * C;
  out += (size_t)e * out_estride;
  __shared__ unsigned int lt[64 * 33];

  const int tid = threadIdx.x;
  const int m = tid & 15, qq = tid >> 4;
#pragma unroll
  for (int rep = 0; rep < 2; ++rep) {
    int rp = qq + rep * 16;
    const float4 a = *(const float4*)(in + (size_t)(r0 + rp * 2) * C + c0 + m * 4);
    const float4 b = *(const float4*)(in + (size_t)(r0 + rp * 2 + 1) * C + c0 + m * 4);
#pragma unroll
    for (int j = 0; j < 4; ++j) {
      unsigned short lo = __builtin_bit_cast(unsigned short, (bf16)((&a.x)[j]));
      unsigned short hi = __builtin_bit_cast(unsigned short, (bf16)((&b.x)[j]));
      lt[(m * 4 + j) * 33 + rp] = (unsigned int)lo | ((unsigned int)hi << 16);
    }
  }
  __syncthreads();
  const int c = tid >> 2, dw0 = (tid & 3) * 8;
  unsigned int vv[8];
#pragma unroll
  for (int j = 0; j < 8; ++j) vv[j] = lt[c * 33 + dw0 + j];
  int orow = c0 + c;
  if (mode >= 0) orow = ((orow >> 4) << 5) | (orow & 15) | mode;
  uint4* dst = (uint4*)(out + (size_t)orow * R + r0 + dw0 * 2);
  dst[0] = make_uint4(vv[0], vv[1], vv[2], vv[3]);
  dst[1] = make_uint4(vv[4], vv[5], vv[6], vv[7]);
}

// ============================== GEMM1 ====================================
// h-half = gate * (X@W1e) * silu(X@W3e), N-half of the interleaved [W1;W3].
// All experts in one dispatch; hbuf rows globally packed by prefix+grow.
// XCD swizzle: work = (w&7)*4096 + (w>>3); n fastest, e outermost -> one
// expert per XCD, A-tile fetched once, B-half L2-resident.
// Inner: R3-proven 2-buf LDS (33KB), 1 syncthreads/K-step, XOR chunk swizzle.
__global__ __launch_bounds__(256, 2) void gemm1_kernel(
    const bf16* __restrict__ xbf, const bf16* __restrict__ W13T,
    const int* __restrict__ counts, const int* __restrict__ lists,
    const float* __restrict__ gates, bf16* __restrict__ hbuf, int half) {
  // ---- XCD-aware decode (W = 16*256*8 = 32768, %8==0 -> bijective) ----
  const int flat =
      (int)blockIdx.x + 16 * ((int)blockIdx.y + 256 * (int)blockIdx.z);
  const int swz = (flat & 7) * 4096 + (flat >> 3);
  const int nb = swz & 15;
  const int mb = (swz >> 4) & 255;
  const int e = swz >> 12;

  const int count = counts[e];
  const int m0 = mb * 128;
  if (m0 >= count) return;
  int hbase = 0;
  for (int j = 0; j < e; ++j) hbase += counts[j];
  const int n0 = nb * 128 + half * (2 * HH);  // global interleaved col
  const int* list_e = lists + e * NTOK;
  const bf16* Be = W13T + (size_t)e * (2 * H_) * D_;

  __shared__ bf16 sA[2 * 128 * 32];
  __shared__ bf16 sB[2 * 128 * 32];
  __shared__ int stok[128];
  __shared__ float sgate[128];

  const int tid = threadIdx.x;
  if (tid < 128) {
    int rg = m0 + tid;
    int pr = (rg < count) ? list_e[rg] : 0;
    stok[tid] = pr >> 1;
    sgate[tid] = (rg < count) ? gates[pr] : 0.f;
  }
  __syncthreads();

  const int wave = tid >> 6, lane = tid & 63;
  // staging map: LDS slot (row = wave*16 + (lane>>2), chunk = lane&3), linear dest.
  // source chunk permuted by s(row) = (lane>>3)&3 so the swizzled READ matches.
  const int rsub = lane >> 2, kq = lane & 3;
  const int scol = (kq ^ ((lane >> 3) & 3)) * 8;
  const int rA0 = wave * 16 + rsub, rA1 = 64 + wave * 16 + rsub;
  const bf16* aP0 = xbf + (size_t)stok[rA0] * D_ + scol;
  const bf16* aP1 = xbf + (size_t)stok[rA1] * D_ + scol;
  const bf16* bP0 = Be + (size_t)(n0 + rA0) * D_ + scol;
  const bf16* bP1 = Be + (size_t)(n0 + rA1) * D_ + scol;
  bf16* lA0 = sA + wave * 512;
  bf16* lA1 = sA + (wave + 4) * 512;
  bf16* lB0 = sB + wave * 512;
  bf16* lB1 = sB + (wave + 4) * 512;

  const int wm = wave >> 1, wn = wave & 1;
  const int lm = lane & 15, q = lane >> 4;
  const int rq = (q ^ ((lm >> 1) & 3)) * 8;  // swizzled read chunk (2-way banks)
  const bf16* aRd = sA + (wm * 64 + lm) * 32 + rq;
  const bf16* bRd = sB + (wn * 64 + lm) * 32 + rq;

  f32x4 acc[4][4] = {};

  // prologue: stage tile 0 into buf 0
  gl16(aP0, lA0);
  gl16(aP1, lA1);
  gl16(bP0, lB0);
  gl16(bP1, lB1);
  __syncthreads();

  int cur = 0;
  for (int t = 1; t < D_ / 32; ++t) {
    const int koff = t * 32;
    const int nxt = (cur ^ 1) * 4096;
    gl16(aP0 + koff, lA0 + nxt);  // prefetch next tile (hidden under MFMA)
    gl16(aP1 + koff, lA1 + nxt);
    gl16(bP0 + koff, lB0 + nxt);
    gl16(bP1 + koff, lB1 + nxt);
    const bf16* aR = aRd + cur * 4096;
    const bf16* bR = bRd + cur * 4096;
    bf16x8 af[4], bf_[4];
#pragma unroll
    for (int i = 0; i < 4; ++i) {
      af[i] = *(const bf16x8*)(aR + i * 512);
      bf_[i] = *(const bf16x8*)(bR + i * 512);
    }
#pragma unroll
    for (int mt = 0; mt < 4; ++mt)
#pragma unroll
      for (int nt = 0; nt < 4; ++nt)
        acc[mt][nt] =
            __builtin_amdgcn_mfma_f32_16x16x32_bf16(af[mt], bf_[nt], acc[mt][nt], 0, 0, 0);
    __syncthreads();  // drains prefetch (vmcnt) + all reads of buf cur
    cur ^= 1;
  }
  {  // last tile: compute only
    const bf16* aR = aRd + cur * 4096;
    const bf16* bR = bRd + cur * 4096;
    bf16x8 af[4], bf_[4];
#pragma unroll
    for (int i = 0; i < 4; ++i) {
      af[i] = *(const bf16x8*)(aR + i * 512);
      bf_[i] = *(const bf16x8*)(bR + i * 512);
    }
#pragma unroll
    for (int mt = 0; mt < 4; ++mt)
#pragma unroll
      for (int nt = 0; nt < 4; ++nt)
        acc[mt][nt] =
            __builtin_amdgcn_mfma_f32_16x16x32_bf16(af[mt], bf_[nt], acc[mt][nt], 0, 0, 0);
  }

  // epilogue: nt pairs (2u = W1 frag, 2u+1 = W3 frag) -> half-local h col
  const int hb = nb * 64 + wn * 32;  // (nb*128)/2 + wn*32, half-local
#pragma unroll
  for (int mt = 0; mt < 4; ++mt) {
#pragma unroll
    for (int u = 0; u < 2; ++u) {
#pragma unroll
      for (int r = 0; r < 4; ++r) {
        int lrow = wm * 64 + mt * 16 + q * 4 + r;  // C/D: row=(lane>>4)*4+reg, col=lane&15
        int grow = m0 + lrow;
        if (grow < count) {
          float v1 = acc[mt][2 * u][r];
          float v3 = acc[mt][2 * u + 1][r];
          float g = v1 * (v3 / (1.f + __expf(-v3))) * sgate[lrow];
          hbuf[(size_t)(hbase + grow) * HH + hb + u * 16 + lm] = (bf16)g;
        }
      }
    }
  }
}

// ============================== GEMM2 ====================================
// y += h-half @ W2e^T[half K-rows]; scatter via atomicAdd. All experts in
// one dispatch per half. XCD swizzle: work = (w&7)*1024 + (w>>3); n fastest,
// e outermost. Inner: R4-proven NBUF=4, stage-first, counted vmcnt(8)/4/0.
__global__ __launch_bounds__(256, 2) void gemm2_kernel(const bf16* __restrict__ hbuf,
                                                       const bf16* __restrict__ W2T,
                                                       const int* __restrict__ counts,
                                                       const int* __restrict__ lists,
                                                       float* __restrict__ y, int half) {
  // ---- XCD-aware decode (W = 4*256*8 = 8192, %8==0 -> bijective) ----
  const int flat =
      (int)blockIdx.x + 4 * ((int)blockIdx.y + 256 * (int)blockIdx.z);
  const int swz = (flat & 7) * 1024 + (flat >> 3);
  const int nb = swz & 3;
  const int mb = (swz >> 2) & 255;
  const int e = swz >> 10;

  const int count = counts[e];
  const int m0 = mb * 128;
  if (m0 >= count) return;
  int hbase = 0;
  for (int j = 0; j < e; ++j) hbase += counts[j];
  const int n0 = nb * 128;   // over D
  const int kb = half * HH;  // K chunk base in W2T cols
  const bf16* W2e = W2T + (size_t)e * D_ * H_;
  const int* list_e = lists + e * NTOK;

  __shared__ bf16 sA[4 * 128 * 32];
  __shared__ bf16 sB[4 * 128 * 32];
  __shared__ int stok[128];

  const int tid = threadIdx.x;
  if (tid < 128) {
    int rg = m0 + tid;
    stok[tid] = (rg < count) ? (list_e[rg] >> 1) : 0;
  }
  __syncthreads();

  const int wave = tid >> 6, lane = tid & 63;
  const int rsub = lane >> 2, kq = lane & 3;
  const int scol = (kq ^ ((lane >> 3) & 3)) * 8;
  const int rA0 = wave * 16 + rsub, rA1 = 64 + wave * 16 + rsub;
  // clamp packed-row reads at buffer end (tail rows of last expert)
  int ra0 = hbase + m0 + rA0;
  int ra1 = hbase + m0 + rA1;
  if (ra0 >= NPAIR) ra0 = NPAIR - 1;
  if (ra1 >= NPAIR) ra1 = NPAIR - 1;
  const bf16* aP0 = hbuf + (size_t)ra0 * HH + scol;
  const bf16* aP1 = hbuf + (size_t)ra1 * HH + scol;
  const bf16* bP0 = W2e + (size_t)(n0 + rA0) * H_ + kb + scol;
  const bf16* bP1 = W2e + (size_t)(n0 + rA1) * H_ + kb + scol;

  const int wm = wave >> 1, wn = wave & 1;
  const int lm = lane & 15, q = lane >> 4;
  const int rq = (q ^ ((lm >> 1) & 3)) * 8;
  const bf16* aRd = sA + (wm * 64 + lm) * 32 + rq;
  const bf16* bRd = sB + (wn * 64 + lm) * 32 + rq;

  f32x4 acc[4][4] = {};

  auto STAGE = [&](int t, int bi) {
    const int ko = t * 32;
    bf16* ba = sA + bi * 4096;
    bf16* bb = sB + bi * 4096;
    gl16(aP0 + ko, ba + wave * 512);
    gl16(aP1 + ko, ba + (wave + 4) * 512);
    gl16(bP0 + ko, bb + wave * 512);
    gl16(bP1 + ko, bb + (wave + 4) * 512);
  };
  auto COMP = [&](int bi) {
    const bf16* aR = aRd + bi * 4096;
    const bf16* bR = bRd + bi * 4096;
    bf16x8 af[4], bf_[4];
#pragma unroll
    for (int i = 0; i < 4; ++i) {
      af[i] = *(const bf16x8*)(aR + i * 512);
      bf_[i] = *(const bf16x8*)(bR + i * 512);
    }
#pragma unroll
    for (int mt = 0; mt < 4; ++mt)
#pragma unroll
      for (int nt = 0; nt < 4; ++nt)
        acc[mt][nt] =
            __builtin_amdgcn_mfma_f32_16x16x32_bf16(af[mt], bf_[nt], acc[mt][nt], 0, 0, 0);
  };

  const int NT = HH / 32;  // 32
  STAGE(0, 0);
  STAGE(1, 1);
  for (int t = 0; t < NT - 2; ++t) {
    STAGE(t + 2, (t + 2) & 3);
    asm volatile("s_waitcnt vmcnt(8) lgkmcnt(0)" ::: "memory");
    __builtin_amdgcn_s_barrier();
    COMP(t & 3);
  }
  asm volatile("s_waitcnt vmcnt(4) lgkmcnt(0)" ::: "memory");
  __builtin_amdgcn_s_barrier();
  COMP((NT - 2) & 3);
  asm volatile("s_waitcnt vmcnt(0) lgkmcnt(0)" ::: "memory");
  __builtin_amdgcn_s_barrier();
  COMP((NT - 1) & 3);

#pragma unroll
  for (int mt = 0; mt < 4; ++mt) {
#pragma unroll
    for (int nt = 0; nt < 4; ++nt) {
#pragma unroll
      for (int r = 0; r < 4; ++r) {
        int lrow = wm * 64 + mt * 16 + q * 4 + r;
        int grow = m0 + lrow;
        if (grow < count) {
          atomicAdd(&y[(size_t)stok[lrow] * D_ + n0 + wn * 64 + nt * 16 + lm], acc[mt][nt][r]);
        }
      }
    }
  }
}

// ============================= finalize ==================================
__global__ __launch_bounds__(256) void finalize_kernel(const float* __restrict__ Wp,
                                                       const float* __restrict__ probSum,
                                                       const float* __restrict__ zSum,
                                                       float* __restrict__ out) {
  __shared__ float pn[P_][E_];
  __shared__ float simAcc;
  const int tid = threadIdx.x;
  if (tid == 0) simAcc = 0.f;
  if (tid < P_) {
    float v[E_], m = -1e30f, s = 0.f;
#pragma unroll
    for (int e = 0; e < E_; ++e) {
      v[e] = Wp[tid * E_ + e];
      m = fmaxf(m, v[e]);
    }
#pragma unroll
    for (int e = 0; e < E_; ++e) {
      float ex = expf(v[e] - m);
      pn[tid][e] = ex;
      s += ex;
    }
#pragma unroll
    for (int e = 0; e < E_; ++e) pn[tid][e] /= s;
  }
  __syncthreads();
  {
    int i = tid >> 4, j = tid & 15;
    if (i != j) {
      float d = 0.f;
#pragma unroll
      for (int e = 0; e < E_; ++e) d += pn[i][e] * pn[j][e];
      atomicAdd(&simAcc, d);
    }
  }
  __syncthreads();
  if (tid == 0) {
    out[0] = zSum[0] / (float)(NTOK * E_) * 0.001f;
    float bl = 0.f;
#pragma unroll
    for (int e = 0; e < E_; ++e) {
      float pm = probSum[e] / (float)NTOK - 1.f / (float)E_;
      bl += pm * pm;
    }
    out[1] = bl / (float)E_;
    out[2] = simAcc / (float)(P_ * P_) * 0.1f;
  }
}

// ============================== launch ===================================
extern "C" void kernel_launch(void* const* d_in, const int* in_sizes, int n_in, void* d_out,
                              int out_size, void* d_ws, size_t ws_size, hipStream_t stream) {
  const float* x = (const float*)d_in[0];
  const int* pids = (const int*)d_in[1];
  const float* Wr = (const float*)d_in[2];
  const float* Wp = (const float*)d_in[3];
  const float* W1 = (const float*)d_in[4];
  const float* W2 = (const float*)d_in[5];
  const float* W3 = (const float*)d_in[6];
  float* y = (float*)d_out;

  if (ws_size < WS_NEEDED) return;

  char* ws = (char*)d_ws;
  int* counts = (int*)ws;
  float* probSum = (float*)(ws + 32);
  float* zSum = (float*)(ws + 64);
  float* gates = (float*)(ws + OFF_GATES);
  int* lists = (int*)(ws + OFF_LIST);
  bf16* xbf = (bf16*)(ws + OFF_XBF);
  bf16* W13T = (bf16*)(ws + OFF_W13T);
  bf16* W2T = (bf16*)(ws + OFF_W2T);
  bf16* hbuf = (bf16*)(ws + OFF_HBUF);

  hipMemsetAsync(ws, 0, 256, stream);
  hipMemsetAsync(d_out, 0, (size_t)NTOK * D_ * 4, stream);

  router_kernel<<<dim3(NTOK / 32), 256, 0, stream>>>(x, pids, Wr, Wp, xbf, gates, lists, counts,
                                                     probSum, zSum);
  // W1 -> even 16-col groups, W3 -> odd 16-col groups of W13T [E][2H][D]
  transpose_convert<<<dim3(H_ / 64, D_ / 64, E_), 256, 0, stream>>>(W1, W13T, D_, H_,
                                                                    (size_t)2 * H_ * D_, 0);
  transpose_convert<<<dim3(H_ / 64, D_ / 64, E_), 256, 0, stream>>>(W3, W13T, D_, H_,
                                                                    (size_t)2 * H_ * D_, 16);
  transpose_convert<<<dim3(D_ / 64, H_ / 64, E_), 256, 0, stream>>>(W2, W2T, H_, D_,
                                                                    (size_t)H_ * D_, -1);

  for (int half = 0; half < 2; ++half) {
    gemm1_kernel<<<dim3((2 * HH) / 128, NTOK / 128, E_), 256, 0, stream>>>(
        xbf, W13T, counts, lists, gates, hbuf, half);
    gemm2_kernel<<<dim3(D_ / 128, NTOK / 128, E_), 256, 0, stream>>>(hbuf, W2T, counts, lists,
                                                                     y, half);
  }
  finalize_kernel<<<1, 256, 0, stream>>>(Wp, probSum, zSum, y + (size_t)NTOK * D_);
}

// Round 9
// 962.908 us; speedup vs baseline: 1.0477x; 1.0477x over previous
//
#include <hip/hip_runtime.h>
#include <hip/hip_bf16.h>
#include <math.h>

// Pattern-aware MoE, MI355X. Sparse top-2 dispatch with bf16 MFMA grouped GEMMs.
// B=8 S=4096 D=512 H=2048 E=8 P=16 K=2.
// R11: revert R10's XCD swizzle (FETCH dropped 4.4x but time rose — L3 was
//   absorbing the refetch; swizzle hurt scheduling). gemm1 widened to
//   128(M)x256(N) tile, 512 threads, 8 waves (2Mx4N, 64x64 each): same
//   per-wave acc (64 VGPR) + same R3 2-buf pipeline, but 3 gl16/K-step for
//   2x output, A-gather volume per FLOP halved (8 vs 16 N-blocks), 48KB LDS.
//   gemm2 byte-identical to R9 (proven NBUF=4 counted vmcnt).

#define B_ 8
#define S_ 4096
#define D_ 512
#define H_ 2048
#define HH (H_ / 2)         // 1024 half width
#define E_ 8
#define P_ 16
#define NTOK (B_ * S_)      // 32768
#define NPAIR (NTOK * 2)    // 65536

typedef __bf16 bf16;
typedef __bf16 bf16x8 __attribute__((ext_vector_type(8)));
typedef float f32x4 __attribute__((ext_vector_type(4)));

// ---- workspace layout (bytes) ----
#define OFF_GATES 256
#define OFF_LIST (OFF_GATES + NPAIR * 4)
#define OFF_XBF (OFF_LIST + E_ * NTOK * 4)
#define OFF_W13T (OFF_XBF + (size_t)NTOK * D_ * 2)                // [E][2H][D] interleaved
#define OFF_W2T (OFF_W13T + (size_t)E_ * 2 * H_ * D_ * 2)
#define OFF_HBUF (OFF_W2T + (size_t)E_ * D_ * H_ * 2)
#define WS_NEEDED (OFF_HBUF + (size_t)NPAIR * HH * 2)  // ~209 MiB

// async global->LDS, 16B per lane; LDS dest = base + lane*16 (wave-uniform base)
__device__ __forceinline__ void gl16(const bf16* g, bf16* l) {
  __builtin_amdgcn_global_load_lds((const __attribute__((address_space(1))) unsigned int*)g,
                                   (__attribute__((address_space(3))) unsigned int*)l, 16, 0, 0);
}

// ============================ router =====================================
__global__ __launch_bounds__(256) void router_kernel(
    const float* __restrict__ x, const int* __restrict__ pids,
    const float* __restrict__ Wr, const float* __restrict__ Wp,
    bf16* __restrict__ xbf, float* __restrict__ gates, int* __restrict__ lists,
    int* __restrict__ counts, float* __restrict__ probSum, float* __restrict__ zSum) {
  __shared__ float xs[32 * 516];     // stride 516: 8 rows/wave land on distinct banks
  __shared__ float wr_s[E_ * 516];   // [e][d], stride 516
  __shared__ float wp_s[E_];
  __shared__ float probAcc[E_];
  __shared__ float zAcc;
  __shared__ int lcnt[E_], lbase[E_];
  __shared__ float lg_s[32][E_ + 1];

  const int tid = threadIdx.x;
  const int tok0 = blockIdx.x * 32;

  // Wr is [D][E] -> wr_s[e*516 + d]
#pragma unroll
  for (int rep = 0; rep < (D_ * E_) / 256; ++rep) {
    int flat = rep * 256 + tid;
    wr_s[(flat & 7) * 516 + (flat >> 3)] = Wr[flat];
  }
  if (tid < E_) {
    wp_s[tid] = Wp[pids[tok0 >> 12] * E_ + tid];  // blocks never straddle batch rows
    probAcc[tid] = 0.f;
    lcnt[tid] = 0;
  }
  if (tid == 0) zAcc = 0.f;

  // stage x tile + write bf16 copy (both coalesced)
  const float4* x4 = (const float4*)(x + (size_t)tok0 * D_);
#pragma unroll
  for (int rep = 0; rep < 16; ++rep) {
    int idx = rep * 256 + tid;  // float4 index in 32x512 tile
    float4 v = x4[idx];
    int t = idx >> 7;           // 128 float4 per row
    int d = (idx & 127) * 4;
    *(float4*)(xs + t * 516 + d) = v;
    union { unsigned short u[4]; uint2 qq; } pk;
    pk.u[0] = __builtin_bit_cast(unsigned short, (bf16)v.x);
    pk.u[1] = __builtin_bit_cast(unsigned short, (bf16)v.y);
    pk.u[2] = __builtin_bit_cast(unsigned short, (bf16)v.z);
    pk.u[3] = __builtin_bit_cast(unsigned short, (bf16)v.w);
    *(uint2*)(xbf + (size_t)tok0 * D_ + (size_t)idx * 4) = pk.qq;
  }
  __syncthreads();

  const int t = tid >> 3, e = tid & 7;
  const int lane = tid & 63;
  {
    float a0 = 0.f, a1 = 0.f, a2 = 0.f, a3 = 0.f;
    const float* xr = xs + t * 516;
    const float* wr = wr_s + e * 516;
#pragma unroll 8
    for (int d = 0; d < D_; d += 4) {
      float4 xv = *(const float4*)(xr + d);
      float4 wv = *(const float4*)(wr + d);
      a0 += xv.x * wv.x;
      a1 += xv.y * wv.y;
      a2 += xv.z * wv.z;
      a3 += xv.w * wv.w;
    }
    lg_s[t][e] = (a0 + a1) + (a2 + a3) + wp_s[e];
  }
  __syncthreads();

  float v[E_];
#pragma unroll
  for (int k = 0; k < E_; ++k) v[k] = lg_s[t][k];
  const float lg = v[e];
  float m = v[0];
#pragma unroll
  for (int k = 1; k < E_; ++k) m = fmaxf(m, v[k]);
  float s = 0.f;
#pragma unroll
  for (int k = 0; k < E_; ++k) s += expf(v[k] - m);
  float prob = expf(lg - m) / s;
  float z = lg * lg;
  // top-2 (ties -> lower index, matching lax.top_k)
  int i1 = 0;
  float v1 = v[0];
#pragma unroll
  for (int k = 1; k < E_; ++k)
    if (v[k] > v1) { v1 = v[k]; i1 = k; }
  int i2 = -1;
  float v2 = -1e30f;
#pragma unroll
  for (int k = 0; k < E_; ++k)
    if (k != i1 && v[k] > v2) { v2 = v[k]; i2 = k; }

  // stats reductions: same-e lanes are stride-8 within the wave
  float p = prob;
  p += __shfl_xor(p, 8);
  p += __shfl_xor(p, 16);
  p += __shfl_xor(p, 32);
  float zz = z;
#pragma unroll
  for (int off = 1; off < 64; off <<= 1) zz += __shfl_xor(zz, off);
  if (lane < 8) atomicAdd(&probAcc[e], p);
  if (lane == 0) atomicAdd(&zAcc, zz);

  // selection + local list append
  int r = (e == i1) ? 0 : ((e == i2) ? 1 : -1);
  int pos = -1;
  if (r >= 0) {
    float ex = expf(v2 - v1);
    float g = (r == 0) ? 1.f / (1.f + ex) : ex / (1.f + ex);
    gates[(tok0 + t) * 2 + r] = g;
    pos = atomicAdd(&lcnt[e], 1);
  }
  __syncthreads();
  if (tid < E_) lbase[tid] = atomicAdd(&counts[tid], lcnt[tid]);
  __syncthreads();
  if (r >= 0) lists[e * NTOK + lbase[e] + pos] = (tok0 + t) * 2 + r;
  if (tid < E_) atomicAdd(&probSum[tid], probAcc[tid]);
  else if (tid == 8) atomicAdd(zSum, zAcc);
}

// ======================= transpose + fp32->bf16 ==========================
// mode < 0: plain transpose. mode >= 0: W13T interleave remap:
// out row = ((h>>4)<<5) | (h&15) | mode  (mode=0 W1, mode=16 W3).
__global__ __launch_bounds__(256) void transpose_convert(const float* __restrict__ in,
                                                         bf16* __restrict__ out, int R, int C,
                                                         size_t out_estride, int mode) {
  const int e = blockIdx.z;
  const int r0 = blockIdx.y * 64, c0 = blockIdx.x * 64;
  in += (size_t)e * R * C;
  out += (size_t)e * out_estride;
  __shared__ unsigned int lt[64 * 33];

  const int tid = threadIdx.x;
  const int m = tid & 15, qq = tid >> 4;
#pragma unroll
  for (int rep = 0; rep < 2; ++rep) {
    int rp = qq + rep * 16;
    const float4 a = *(const float4*)(in + (size_t)(r0 + rp * 2) * C + c0 + m * 4);
    const float4 b = *(const float4*)(in + (size_t)(r0 + rp * 2 + 1) * C + c0 + m * 4);
#pragma unroll
    for (int j = 0; j < 4; ++j) {
      unsigned short lo = __builtin_bit_cast(unsigned short, (bf16)((&a.x)[j]));
      unsigned short hi = __builtin_bit_cast(unsigned short, (bf16)((&b.x)[j]));
      lt[(m * 4 + j) * 33 + rp] = (unsigned int)lo | ((unsigned int)hi << 16);
    }
  }
  __syncthreads();
  const int c = tid >> 2, dw0 = (tid & 3) * 8;
  unsigned int vv[8];
#pragma unroll
  for (int j = 0; j < 8; ++j) vv[j] = lt[c * 33 + dw0 + j];
  int orow = c0 + c;
  if (mode >= 0) orow = ((orow >> 4) << 5) | (orow & 15) | mode;
  uint4* dst = (uint4*)(out + (size_t)orow * R + r0 + dw0 * 2);
  dst[0] = make_uint4(vv[0], vv[1], vv[2], vv[3]);
  dst[1] = make_uint4(vv[4], vv[5], vv[6], vv[7]);
}

// ============================== GEMM1 ====================================
// h-half = gate * (X@W1e) * silu(X@W3e), N-half of interleaved [W1;W3].
// 128(M)x256(N) tile, 512 threads, 8 waves (2Mx4N -> each 64x64, acc 64 VGPR).
// R3-proven 2-buf pipeline: prefetch-next (3 gl16) + 1 syncthreads/K-step.
// A slice: 1 gl16/wave (rows wave*16..+16); B: 2 gl16/wave (rows r, 128+r).
__global__ __launch_bounds__(512, 4) void gemm1_kernel(
    const bf16* __restrict__ xbf, const bf16* __restrict__ W13T,
    const int* __restrict__ counts, const int* __restrict__ lists,
    const float* __restrict__ gates, bf16* __restrict__ hbuf, int half) {
  const int e = (int)blockIdx.z;
  const int count = counts[e];
  const int m0 = blockIdx.y * 128;
  if (m0 >= count) return;
  int hbase = 0;
  for (int j = 0; j < e; ++j) hbase += counts[j];
  const int nb = (int)blockIdx.x;             // 8 n-blocks of 256
  const int n0 = nb * 256 + half * (2 * HH);  // global interleaved col
  const int* list_e = lists + e * NTOK;
  const bf16* Be = W13T + (size_t)e * (2 * H_) * D_;

  __shared__ bf16 sA[2 * 128 * 32];  // 16 KB
  __shared__ bf16 sB[2 * 256 * 32];  // 32 KB
  __shared__ int stok[128];
  __shared__ float sgate[128];

  const int tid = threadIdx.x;
  if (tid < 128) {
    int rg = m0 + tid;
    int pr = (rg < count) ? list_e[rg] : 0;
    stok[tid] = pr >> 1;
    sgate[tid] = (rg < count) ? gates[pr] : 0.f;
  }
  __syncthreads();

  const int wave = tid >> 6, lane = tid & 63;  // wave 0..7
  // staging map (per 16-row slice): row = slice + (lane>>2), chunk = lane&3,
  // linear LDS dest; source chunk permuted by (row>>1)&3 = (lane>>3)&3 so the
  // swizzled READ matches (2-way banks).
  const int rsub = lane >> 2, kq = lane & 3;
  const int scol = (kq ^ ((lane >> 3) & 3)) * 8;
  const int rS = wave * 16 + rsub;  // 0..127
  const bf16* aP0 = xbf + (size_t)stok[rS] * D_ + scol;
  const bf16* bP0 = Be + (size_t)(n0 + rS) * D_ + scol;
  const bf16* bP1 = Be + (size_t)(n0 + 128 + rS) * D_ + scol;
  bf16* lA0 = sA + wave * 512;
  bf16* lB0 = sB + wave * 512;
  bf16* lB1 = sB + (wave + 8) * 512;

  const int wm = wave >> 2, wn = wave & 3;  // 2M x 4N
  const int lm = lane & 15, q = lane >> 4;
  const int rq = (q ^ ((lm >> 1) & 3)) * 8;  // swizzled read chunk
  const bf16* aRd = sA + (wm * 64 + lm) * 32 + rq;
  const bf16* bRd = sB + (wn * 64 + lm) * 32 + rq;

  f32x4 acc[4][4] = {};

  // prologue: stage tile 0 into buf 0
  gl16(aP0, lA0);
  gl16(bP0, lB0);
  gl16(bP1, lB1);
  __syncthreads();

  int cur = 0;
  for (int t = 1; t < D_ / 32; ++t) {
    const int koff = t * 32;
    const int nxtA = (cur ^ 1) * 4096;
    const int nxtB = (cur ^ 1) * 8192;
    gl16(aP0 + koff, lA0 + nxtA);  // prefetch next tile (hidden under MFMA)
    gl16(bP0 + koff, lB0 + nxtB);
    gl16(bP1 + koff, lB1 + nxtB);
    const bf16* aR = aRd + cur * 4096;
    const bf16* bR = bRd + cur * 8192;
    bf16x8 af[4], bf_[4];
#pragma unroll
    for (int i = 0; i < 4; ++i) {
      af[i] = *(const bf16x8*)(aR + i * 512);
      bf_[i] = *(const bf16x8*)(bR + i * 512);
    }
#pragma unroll
    for (int mt = 0; mt < 4; ++mt)
#pragma unroll
      for (int nt = 0; nt < 4; ++nt)
        acc[mt][nt] =
            __builtin_amdgcn_mfma_f32_16x16x32_bf16(af[mt], bf_[nt], acc[mt][nt], 0, 0, 0);
    __syncthreads();  // drains prefetch (vmcnt) + all reads of buf cur
    cur ^= 1;
  }
  {  // last tile: compute only
    const bf16* aR = aRd + cur * 4096;
    const bf16* bR = bRd + cur * 8192;
    bf16x8 af[4], bf_[4];
#pragma unroll
    for (int i = 0; i < 4; ++i) {
      af[i] = *(const bf16x8*)(aR + i * 512);
      bf_[i] = *(const bf16x8*)(bR + i * 512);
    }
#pragma unroll
    for (int mt = 0; mt < 4; ++mt)
#pragma unroll
      for (int nt = 0; nt < 4; ++nt)
        acc[mt][nt] =
            __builtin_amdgcn_mfma_f32_16x16x32_bf16(af[mt], bf_[nt], acc[mt][nt], 0, 0, 0);
  }

  // epilogue: nt pairs (2u = W1 frag, 2u+1 = W3 frag) -> half-local h col
  const int hb = nb * 128 + wn * 32;  // (nb*256 + wn*64)/2, half-local
#pragma unroll
  for (int mt = 0; mt < 4; ++mt) {
#pragma unroll
    for (int u = 0; u < 2; ++u) {
#pragma unroll
      for (int r = 0; r < 4; ++r) {
        int lrow = wm * 64 + mt * 16 + q * 4 + r;  // C/D: row=(lane>>4)*4+reg, col=lane&15
        int grow = m0 + lrow;
        if (grow < count) {
          float v1 = acc[mt][2 * u][r];
          float v3 = acc[mt][2 * u + 1][r];
          float g = v1 * (v3 / (1.f + __expf(-v3))) * sgate[lrow];
          hbuf[(size_t)(hbase + grow) * HH + hb + u * 16 + lm] = (bf16)g;
        }
      }
    }
  }
}

// ============================== GEMM2 ====================================
// y += h-half @ W2e^T[half K-rows]; scatter via atomicAdd. All experts in
// one dispatch per half (z=8). A = packed hbuf rows (contiguous), K=HH.
// R4-proven inner: NBUF=4, stage-first, counted vmcnt(8)/4/0. (R9 verbatim.)
__global__ __launch_bounds__(256, 2) void gemm2_kernel(const bf16* __restrict__ hbuf,
                                                       const bf16* __restrict__ W2T,
                                                       const int* __restrict__ counts,
                                                       const int* __restrict__ lists,
                                                       float* __restrict__ y, int half) {
  const int e = (int)blockIdx.z;
  const int count = counts[e];
  const int m0 = blockIdx.y * 128;
  if (m0 >= count) return;
  int hbase = 0;
  for (int j = 0; j < e; ++j) hbase += counts[j];
  const int n0 = blockIdx.x * 128;  // over D
  const int kb = half * HH;         // K chunk base in W2T cols
  const bf16* W2e = W2T + (size_t)e * D_ * H_;
  const int* list_e = lists + e * NTOK;

  __shared__ bf16 sA[4 * 128 * 32];
  __shared__ bf16 sB[4 * 128 * 32];
  __shared__ int stok[128];

  const int tid = threadIdx.x;
  if (tid < 128) {
    int rg = m0 + tid;
    stok[tid] = (rg < count) ? (list_e[rg] >> 1) : 0;
  }
  __syncthreads();

  const int wave = tid >> 6, lane = tid & 63;
  const int rsub = lane >> 2, kq = lane & 3;
  const int scol = (kq ^ ((lane >> 3) & 3)) * 8;
  const int rA0 = wave * 16 + rsub, rA1 = 64 + wave * 16 + rsub;
  // clamp packed-row reads at buffer end (tail rows of last expert)
  int ra0 = hbase + m0 + rA0;
  int ra1 = hbase + m0 + rA1;
  if (ra0 >= NPAIR) ra0 = NPAIR - 1;
  if (ra1 >= NPAIR) ra1 = NPAIR - 1;
  const bf16* aP0 = hbuf + (size_t)ra0 * HH + scol;
  const bf16* aP1 = hbuf + (size_t)ra1 * HH + scol;
  const bf16* bP0 = W2e + (size_t)(n0 + rA0) * H_ + kb + scol;
  const bf16* bP1 = W2e + (size_t)(n0 + rA1) * H_ + kb + scol;

  const int wm = wave >> 1, wn = wave & 1;
  const int lm = lane & 15, q = lane >> 4;
  const int rq = (q ^ ((lm >> 1) & 3)) * 8;
  const bf16* aRd = sA + (wm * 64 + lm) * 32 + rq;
  const bf16* bRd = sB + (wn * 64 + lm) * 32 + rq;

  f32x4 acc[4][4] = {};

  auto STAGE = [&](int t, int bi) {
    const int ko = t * 32;
    bf16* ba = sA + bi * 4096;
    bf16* bb = sB + bi * 4096;
    gl16(aP0 + ko, ba + wave * 512);
    gl16(aP1 + ko, ba + (wave + 4) * 512);
    gl16(bP0 + ko, bb + wave * 512);
    gl16(bP1 + ko, bb + (wave + 4) * 512);
  };
  auto COMP = [&](int bi) {
    const bf16* aR = aRd + bi * 4096;
    const bf16* bR = bRd + bi * 4096;
    bf16x8 af[4], bf_[4];
#pragma unroll
    for (int i = 0; i < 4; ++i) {
      af[i] = *(const bf16x8*)(aR + i * 512);
      bf_[i] = *(const bf16x8*)(bR + i * 512);
    }
#pragma unroll
    for (int mt = 0; mt < 4; ++mt)
#pragma unroll
      for (int nt = 0; nt < 4; ++nt)
        acc[mt][nt] =
            __builtin_amdgcn_mfma_f32_16x16x32_bf16(af[mt], bf_[nt], acc[mt][nt], 0, 0, 0);
  };

  const int NT = HH / 32;  // 32
  STAGE(0, 0);
  STAGE(1, 1);
  for (int t = 0; t < NT - 2; ++t) {
    STAGE(t + 2, (t + 2) & 3);
    asm volatile("s_waitcnt vmcnt(8) lgkmcnt(0)" ::: "memory");
    __builtin_amdgcn_s_barrier();
    COMP(t & 3);
  }
  asm volatile("s_waitcnt vmcnt(4) lgkmcnt(0)" ::: "memory");
  __builtin_amdgcn_s_barrier();
  COMP((NT - 2) & 3);
  asm volatile("s_waitcnt vmcnt(0) lgkmcnt(0)" ::: "memory");
  __builtin_amdgcn_s_barrier();
  COMP((NT - 1) & 3);

#pragma unroll
  for (int mt = 0; mt < 4; ++mt) {
#pragma unroll
    for (int nt = 0; nt < 4; ++nt) {
#pragma unroll
      for (int r = 0; r < 4; ++r) {
        int lrow = wm * 64 + mt * 16 + q * 4 + r;
        int grow = m0 + lrow;
        if (grow < count) {
          atomicAdd(&y[(size_t)stok[lrow] * D_ + n0 + wn * 64 + nt * 16 + lm], acc[mt][nt][r]);
        }
      }
    }
  }
}

// ============================= finalize ==================================
__global__ __launch_bounds__(256) void finalize_kernel(const float* __restrict__ Wp,
                                                       const float* __restrict__ probSum,
                                                       const float* __restrict__ zSum,
                                                       float* __restrict__ out) {
  __shared__ float pn[P_][E_];
  __shared__ float simAcc;
  const int tid = threadIdx.x;
  if (tid == 0) simAcc = 0.f;
  if (tid < P_) {
    float v[E_], m = -1e30f, s = 0.f;
#pragma unroll
    for (int e = 0; e < E_; ++e) {
      v[e] = Wp[tid * E_ + e];
      m = fmaxf(m, v[e]);
    }
#pragma unroll
    for (int e = 0; e < E_; ++e) {
      float ex = expf(v[e] - m);
      pn[tid][e] = ex;
      s += ex;
    }
#pragma unroll
    for (int e = 0; e < E_; ++e) pn[tid][e] /= s;
  }
  __syncthreads();
  {
    int i = tid >> 4, j = tid & 15;
    if (i != j) {
      float d = 0.f;
#pragma unroll
      for (int e = 0; e < E_; ++e) d += pn[i][e] * pn[j][e];
      atomicAdd(&simAcc, d);
    }
  }
  __syncthreads();
  if (tid == 0) {
    out[0] = zSum[0] / (float)(NTOK * E_) * 0.001f;
    float bl = 0.f;
#pragma unroll
    for (int e = 0; e < E_; ++e) {
      float pm = probSum[e] / (float)NTOK - 1.f / (float)E_;
      bl += pm * pm;
    }
    out[1] = bl / (float)E_;
    out[2] = simAcc / (float)(P_ * P_) * 0.1f;
  }
}

// ============================== launch ===================================
extern "C" void kernel_launch(void* const* d_in, const int* in_sizes, int n_in, void* d_out,
                              int out_size, void* d_ws, size_t ws_size, hipStream_t stream) {
  const float* x = (const float*)d_in[0];
  const int* pids = (const int*)d_in[1];
  const float* Wr = (const float*)d_in[2];
  const float* Wp = (const float*)d_in[3];
  const float* W1 = (const float*)d_in[4];
  const float* W2 = (const float*)d_in[5];
  const float* W3 = (const float*)d_in[6];
  float* y = (float*)d_out;

  if (ws_size < WS_NEEDED) return;

  char* ws = (char*)d_ws;
  int* counts = (int*)ws;
  float* probSum = (float*)(ws + 32);
  float* zSum = (float*)(ws + 64);
  float* gates = (float*)(ws + OFF_GATES);
  int* lists = (int*)(ws + OFF_LIST);
  bf16* xbf = (bf16*)(ws + OFF_XBF);
  bf16* W13T = (bf16*)(ws + OFF_W13T);
  bf16* W2T = (bf16*)(ws + OFF_W2T);
  bf16* hbuf = (bf16*)(ws + OFF_HBUF);

  hipMemsetAsync(ws, 0, 256, stream);
  hipMemsetAsync(d_out, 0, (size_t)NTOK * D_ * 4, stream);

  router_kernel<<<dim3(NTOK / 32), 256, 0, stream>>>(x, pids, Wr, Wp, xbf, gates, lists, counts,
                                                     probSum, zSum);
  // W1 -> even 16-col groups, W3 -> odd 16-col groups of W13T [E][2H][D]
  transpose_convert<<<dim3(H_ / 64, D_ / 64, E_), 256, 0, stream>>>(W1, W13T, D_, H_,
                                                                    (size_t)2 * H_ * D_, 0);
  transpose_convert<<<dim3(H_ / 64, D_ / 64, E_), 256, 0, stream>>>(W3, W13T, D_, H_,
                                                                    (size_t)2 * H_ * D_, 16);
  transpose_convert<<<dim3(D_ / 64, H_ / 64, E_), 256, 0, stream>>>(W2, W2T, H_, D_,
                                                                    (size_t)H_ * D_, -1);

  for (int half = 0; half < 2; ++half) {
    gemm1_kernel<<<dim3((2 * HH) / 256, NTOK / 128, E_), 512, 0, stream>>>(
        xbf, W13T, counts, lists, gates, hbuf, half);
    gemm2_kernel<<<dim3(D_ / 128, NTOK / 128, E_), 256, 0, stream>>>(hbuf, W2T, counts, lists,
                                                                     y, half);
  }
  finalize_kernel<<<1, 256, 0, stream>>>(Wp, probSum, zSum, y + (size_t)NTOK * D_);
}